// Round 5
// baseline (2101.703 us; speedup 1.0000x reference)
//
#include <hip/hip_runtime.h>
#include <hip/hip_bf16.h>

// ---------------- problem constants ----------------
#define NWIN   960
#define PP     144          // patches per window
#define CC     192          // dim
#define HH     6            // heads
#define DD     32           // head dim
#define TT     64           // type_of_windows
#define PQ     (PP*PP)      // 20736
#define MROWS  (NWIN*PP)    // 138240
#define NQKV   576
#define QSCALE 0.17677669529663687f   // 32^-0.5

using f32x4 = __attribute__((ext_vector_type(4))) float;
using s16x8 = __attribute__((ext_vector_type(8))) short;

// ---------------- bf16 split helpers ----------------
__device__ inline unsigned short f2bf(float x) {
    __hip_bfloat16 b = __float2bfloat16(x);
    return *reinterpret_cast<unsigned short*>(&b);
}
__device__ inline float bf2f(unsigned short u) {
    __hip_bfloat16 b = *reinterpret_cast<__hip_bfloat16*>(&u);
    return __bfloat162float(b);
}
// pack fp32 as (lo<<16)|hi, hi=bf16(x), lo=bf16(x-hi)
__device__ inline unsigned pack_hl(float x) {
    unsigned short hi = f2bf(x);
    unsigned short lo = f2bf(x - bf2f(hi));
    return ((unsigned)lo << 16) | (unsigned)hi;
}

struct FragHL { s16x8 hi; s16x8 lo; };

// A/B fragment loader: slot (lane, j) <- M[row0 + (lane&15)][8*(lane>>4)+j]
// Same k-bijection used for BOTH operands of every MFMA -> HW k-map cancels.
__device__ inline FragHL load_frag_hl(const unsigned* base, int row0, int stride) {
    int lane = threadIdx.x & 63;
    const unsigned* p = base + (row0 + (lane & 15)) * stride + 8 * (lane >> 4);
    FragHL f;
#pragma unroll
    for (int j = 0; j < 8; ++j) {
        unsigned u = p[j];
        f.hi[j] = (short)(u & 0xffffu);
        f.lo[j] = (short)(u >> 16);
    }
    return f;
}
__device__ inline s16x8 load_frag_bf(const unsigned short* base, int row0,
                                     int stride, int koff) {
    int lane = threadIdx.x & 63;
    const unsigned short* p = base + (row0 + (lane & 15)) * stride + koff + 8 * (lane >> 4);
    s16x8 f;
#pragma unroll
    for (int j = 0; j < 8; ++j) f[j] = (short)p[j];
    return f;
}
// 3-term split product: (Ahi+Alo)(Bhi+Blo) - AloBlo  ~= fp32 accuracy
__device__ inline f32x4 mfma3(const FragHL& a, const FragHL& b, f32x4 c) {
    c = __builtin_amdgcn_mfma_f32_16x16x32_bf16(a.hi, b.hi, c, 0, 0, 0);
    c = __builtin_amdgcn_mfma_f32_16x16x32_bf16(a.hi, b.lo, c, 0, 0, 0);
    c = __builtin_amdgcn_mfma_f32_16x16x32_bf16(a.lo, b.hi, c, 0, 0, 0);
    return c;
}

// ---------------- K0: bias expansion (verified, unchanged) ----------------
__global__ __launch_bounds__(256) void k0_bias_expand(
    const float* __restrict__ table, const int* __restrict__ pidx,
    float* __restrict__ bias_ws)
{
    int pq = blockIdx.x * 256 + threadIdx.x;
    int idx = pidx[pq];
    const float* row = table + (long)idx * 384;
    for (int th = 0; th < 384; ++th) {
        bias_ws[(unsigned)th * PQ + pq] = row[th];
    }
}

// ---------------- K2: fused QKV + attention, MFMA ----------------
// One block per (w,h). 4 waves own M-tiles {wv, wv+4, (wv==0: 8)} of 9.
// LDS layout (bytes):
//   Qs  uint  [144][36] @0      (20736)   } phase>=2   Xs uint[144][36] @0 } staging
//   Ks  uint  [144][36] @20736  (20736)   }            Wt uint[96][36] @20736 }
//   Vt  u16   [32][168] @41472  (10752)
//   Ps  u16   [144][40] @52224  (11520)   -> total 63744 <= 64KB
__global__ __launch_bounds__(256) void k2_mfma(
    const float* __restrict__ x, const float* __restrict__ Wqkv,
    const float* __restrict__ bqkv, const float* __restrict__ mask,
    const float* __restrict__ bias_ws, float* __restrict__ ao)
{
    __shared__ __align__(16) char LDSBUF[63744];
    unsigned*       Qs = (unsigned*)(LDSBUF);
    unsigned*       Ks = (unsigned*)(LDSBUF + 20736);
    unsigned short* Vt = (unsigned short*)(LDSBUF + 41472);
    unsigned short* Ps = (unsigned short*)(LDSBUF + 52224);
    unsigned*       Xs = (unsigned*)(LDSBUF);            // staging overlay
    unsigned*       Wt = (unsigned*)(LDSBUF + 20736);    // staging overlay

    const int tid  = threadIdx.x;
    const int lane = tid & 63;
    const int wv   = tid >> 6;
    // XCD swizzle: keep each window's 6 head-blocks on one XCD (5760 % 8 == 0)
    const int bid = blockIdx.x;
    const int wh  = (bid & 7) * 720 + (bid >> 3);
    const int w = wh / HH, h = wh % HH;
    const int thh = (w % TT) * HH + h;
    const float* xw = x + (long)w * PP * CC;
    const float* mb = mask + (long)w * PQ;
    const float* bb = bias_ws + (long)thh * PQ;

    const int nmt = (wv == 0) ? 3 : 2;
    int mts[3];
    mts[0] = wv; mts[1] = wv + 4; mts[2] = 8;

    const int lgrp = lane >> 4;        // 0..3
    const int l15  = lane & 15;

    // ======== Phase 1: QKV projection, acc1[im][nt]: nt 0-1=Q, 2-3=K, 4-5=V
    f32x4 acc1[3][6];
#pragma unroll
    for (int i = 0; i < 3; ++i)
#pragma unroll
        for (int n = 0; n < 6; ++n) acc1[i][n] = f32x4{0.f, 0.f, 0.f, 0.f};

    for (int kc = 0; kc < CC; kc += 32) {
        __syncthreads();   // prior chunk's fragment reads done
        // stage Xs[144][36] <- x rows, k-chunk, packed hi/lo
        for (int idx = tid; idx < 1152; idx += 256) {     // 144 x 8 float4
            int p  = idx >> 3;
            int c4 = (idx & 7) * 4;
            float4 g = *(const float4*)&xw[p * CC + kc + c4];
            unsigned* dst = Xs + p * 36 + c4;
            dst[0] = pack_hl(g.x); dst[1] = pack_hl(g.y);
            dst[2] = pack_hl(g.z); dst[3] = pack_hl(g.w);
        }
        // stage Wt[96][36]: Wt[n][k] = Wqkv[kc+k][gcol(n)]  (transposed)
        for (int idx = tid; idx < 768; idx += 256) {      // 32 k x 24 float4
            int k  = idx / 24;
            int n4 = (idx % 24) * 4;
            int seg = n4 >> 5;             // 0=Q,1=K,2=V
            int gcol = seg * 192 + h * DD + (n4 & 31);
            float4 g = *(const float4*)&Wqkv[(long)(kc + k) * NQKV + gcol];
            Wt[(n4 + 0) * 36 + k] = pack_hl(g.x);
            Wt[(n4 + 1) * 36 + k] = pack_hl(g.y);
            Wt[(n4 + 2) * 36 + k] = pack_hl(g.z);
            Wt[(n4 + 3) * 36 + k] = pack_hl(g.w);
        }
        __syncthreads();
        FragHL bfr[6];
#pragma unroll
        for (int nt = 0; nt < 6; ++nt) bfr[nt] = load_frag_hl(Wt, nt * 16, 36);
        for (int im = 0; im < nmt; ++im) {
            FragHL a = load_frag_hl(Xs, mts[im] * 16, 36);
#pragma unroll
            for (int nt = 0; nt < 6; ++nt)
                acc1[im][nt] = mfma3(a, bfr[nt], acc1[im][nt]);
        }
    }
    __syncthreads();   // last chunk reads done before overwriting staging region

    // write Q (bias+scale, hi/lo), K (bias, hi/lo), V (bias, bf16 transposed)
    for (int im = 0; im < nmt; ++im) {
        int mrow = mts[im] * 16 + 4 * lgrp;
#pragma unroll
        for (int half = 0; half < 2; ++half) {
            int d = l15 + 16 * half;
            float bq = bqkv[h * DD + d];
            float bk = bqkv[192 + h * DD + d];
            float bv = bqkv[384 + h * DD + d];
            f32x4 q4 = acc1[im][half];
            f32x4 k4 = acc1[im][2 + half];
            f32x4 v4 = acc1[im][4 + half];
#pragma unroll
            for (int r = 0; r < 4; ++r) {
                int row = mrow + r;                       // D-layout: row=4*(l>>4)+r
                Qs[row * 36 + d] = pack_hl((q4[r] + bq) * QSCALE);
                Ks[row * 36 + d] = pack_hl(k4[r] + bk);
                Vt[d * 168 + row] = f2bf(v4[r] + bv);
            }
        }
    }
    // zero-pad Vt kv-cols 144..159 (read by PV chunk 4)
    for (int idx = tid; idx < 512; idx += 256) {
        int d = idx >> 4;
        Vt[d * 168 + 144 + (idx & 15)] = 0;
    }
    __syncthreads();

    // ======== Phase 2: S = Q @ K^T  (full 144x144, no online softmax)
    f32x4 sacc[3][9];
#pragma unroll
    for (int i = 0; i < 3; ++i)
#pragma unroll
        for (int n = 0; n < 9; ++n) sacc[i][n] = f32x4{0.f, 0.f, 0.f, 0.f};

    {
        FragHL aq[3];
        for (int im = 0; im < nmt; ++im) aq[im] = load_frag_hl(Qs, mts[im] * 16, 36);
        for (int nt = 0; nt < 9; ++nt) {
            FragHL b = load_frag_hl(Ks, nt * 16, 36);
            for (int im = 0; im < nmt; ++im)
                sacc[im][nt] = mfma3(aq[im], b, sacc[im][nt]);
        }
    }

    // ======== Phase 2.5: + bias + mask, exact row softmax in registers
    float rsum[3][4];
    for (int im = 0; im < nmt; ++im) {
        int prow = mts[im] * 16 + 4 * lgrp;
#pragma unroll
        for (int nt = 0; nt < 9; ++nt) {
            int qcol = nt * 16 + l15;
#pragma unroll
            for (int r = 0; r < 4; ++r)
                sacc[im][nt][r] += bb[(prow + r) * PP + qcol] + mb[(prow + r) * PP + qcol];
        }
#pragma unroll
        for (int r = 0; r < 4; ++r) {
            float mx = sacc[im][0][r];
#pragma unroll
            for (int nt = 1; nt < 9; ++nt) mx = fmaxf(mx, sacc[im][nt][r]);
#pragma unroll
            for (int off = 1; off < 16; off <<= 1)
                mx = fmaxf(mx, __shfl_xor(mx, off, 16));
            float sum = 0.f;
#pragma unroll
            for (int nt = 0; nt < 9; ++nt) {
                float e = __expf(sacc[im][nt][r] - mx);
                sacc[im][nt][r] = e;              // sacc now holds P (fp32)
                sum += e;
            }
#pragma unroll
            for (int off = 1; off < 16; off <<= 1)
                sum += __shfl_xor(sum, off, 16);
            rsum[im][r] = sum;
        }
    }

    // ======== Phase 3: O = P @ V  (5 kv-chunks of 32, P staged bf16)
    f32x4 oacc[3][2];
#pragma unroll
    for (int i = 0; i < 3; ++i) { oacc[i][0] = f32x4{0.f,0.f,0.f,0.f};
                                  oacc[i][1] = f32x4{0.f,0.f,0.f,0.f}; }

    for (int c = 0; c < 5; ++c) {
        __syncthreads();   // prior chunk's Ps reads done
        for (int im = 0; im < nmt; ++im) {
            int prow = mts[im] * 16 + 4 * lgrp;
#pragma unroll
            for (int half = 0; half < 2; ++half) {
                int nt = 2 * c + half;
                int col = l15 + 16 * half;
#pragma unroll
                for (int r = 0; r < 4; ++r) {
                    unsigned short v = (nt < 9) ? f2bf(sacc[im][nt][r]) : (unsigned short)0;
                    Ps[(prow + r) * 40 + col] = v;
                }
            }
        }
        __syncthreads();
        for (int im = 0; im < nmt; ++im) {
            s16x8 a = load_frag_bf(Ps, mts[im] * 16, 40, 0);
#pragma unroll
            for (int ntd = 0; ntd < 2; ++ntd) {
                s16x8 b = load_frag_bf(Vt, ntd * 16, 168, 32 * c);
                oacc[im][ntd] = __builtin_amdgcn_mfma_f32_16x16x32_bf16(
                    a, b, oacc[im][ntd], 0, 0, 0);
            }
        }
    }

    // ======== finalize: ao[(w*144+p)*192 + h*32 + d] = O / rowsum
    for (int im = 0; im < nmt; ++im) {
        int mrow = mts[im] * 16 + 4 * lgrp;
#pragma unroll
        for (int r = 0; r < 4; ++r) {
            float inv = 1.f / rsum[im][r];
#pragma unroll
            for (int ntd = 0; ntd < 2; ++ntd) {
                int d = l15 + 16 * ntd;
                ao[((long)(w * PP + mrow + r)) * CC + h * DD + d] = oacc[im][ntd][r] * inv;
            }
        }
    }
}

// ---------------- K3: output projection GEMM (verified, unchanged) ----------
#define BM 128
#define BN 64
#define KC 64
__global__ __launch_bounds__(256) void k3_proj(
    const float* __restrict__ ain, const float* __restrict__ Wout,
    const float* __restrict__ bout, float* __restrict__ out)
{
    __shared__ float As[BM][KC + 1];
    __shared__ float Bs[KC][BN];

    const int tid = threadIdx.x;
    const int rowBase = blockIdx.x * BM;
    const int colBase = blockIdx.y * BN;
    const int r0 = (tid >> 4) * 8;
    const int c0 = (tid & 15) * 4;

    float acc[8][4];
#pragma unroll
    for (int i = 0; i < 8; ++i)
#pragma unroll
        for (int j = 0; j < 4; ++j) acc[i][j] = 0.f;

    for (int kc = 0; kc < CC; kc += KC) {
#pragma unroll
        for (int it = 0; it < 8; ++it) {
            int idx = tid + it * 256;
            int row = idx >> 4;
            int kq  = (idx & 15) * 4;
            float4 g = *(const float4*)&ain[(long)(rowBase + row) * CC + kc + kq];
            As[row][kq + 0] = g.x; As[row][kq + 1] = g.y;
            As[row][kq + 2] = g.z; As[row][kq + 3] = g.w;
        }
#pragma unroll
        for (int it = 0; it < 4; ++it) {
            int idx = tid + it * 256;
            int kk = idx >> 4;
            int n0 = (idx & 15) * 4;
            float4 g = *(const float4*)&Wout[(long)(kc + kk) * CC + colBase + n0];
            *(float4*)&Bs[kk][n0] = g;
        }
        __syncthreads();

        for (int kk = 0; kk < KC; ++kk) {
            float4 b4 = *(const float4*)&Bs[kk][c0];
            float a[8];
#pragma unroll
            for (int i = 0; i < 8; ++i) a[i] = As[r0 + i][kk];
#pragma unroll
            for (int i = 0; i < 8; ++i) {
                acc[i][0] = fmaf(a[i], b4.x, acc[i][0]);
                acc[i][1] = fmaf(a[i], b4.y, acc[i][1]);
                acc[i][2] = fmaf(a[i], b4.z, acc[i][2]);
                acc[i][3] = fmaf(a[i], b4.w, acc[i][3]);
            }
        }
        __syncthreads();
    }

    const int c = colBase + c0;
    float b0 = bout[c], b1 = bout[c + 1], b2 = bout[c + 2], b3 = bout[c + 3];
#pragma unroll
    for (int i = 0; i < 8; ++i) {
        int m = rowBase + r0 + i;
        float4 o;
        o.x = acc[i][0] + b0; o.y = acc[i][1] + b1;
        o.z = acc[i][2] + b2; o.w = acc[i][3] + b3;
        *(float4*)&out[(long)m * CC + c] = o;
    }
}

// ---------------- launch ----------------
extern "C" void kernel_launch(void* const* d_in, const int* in_sizes, int n_in,
                              void* d_out, int out_size, void* d_ws, size_t ws_size,
                              hipStream_t stream) {
    const float* x     = (const float*)d_in[0];
    const float* mask  = (const float*)d_in[1];
    const float* Wqkv  = (const float*)d_in[2];
    const float* bqkv  = (const float*)d_in[3];
    const float* Wout  = (const float*)d_in[4];
    const float* bout  = (const float*)d_in[5];
    const float* btab  = (const float*)d_in[6];
    const int*   pidx  = (const int*)d_in[7];
    float* out = (float*)d_out;
    float* ws  = (float*)d_ws;

    float* bws = out;   // expanded bias: first 7,962,624 floats of d_out
    float* ao  = ws;    // attention output: 26,542,080 floats (== out_size bytes)

    hipLaunchKernelGGL(k0_bias_expand, dim3(81), dim3(256), 0, stream,
                       btab, pidx, bws);
    hipLaunchKernelGGL(k2_mfma, dim3(NWIN * HH), dim3(256), 0, stream,
                       x, Wqkv, bqkv, mask, bws, ao);
    hipLaunchKernelGGL(k3_proj, dim3(MROWS / BM, CC / BN), dim3(256), 0, stream,
                       ao, Wout, bout, out);
}